// Round 4
// baseline (379.081 us; speedup 1.0000x reference)
//
#include <hip/hip_runtime.h>
#include <stdint.h>

typedef unsigned short u16;
typedef __attribute__((ext_vector_type(4))) float f32x4;
typedef __attribute__((ext_vector_type(8))) short s16x8;

#define BATCH 4
#define SEQ   2048
#define DIM   1024   // D_IN = STATE = D_OUT
#define KX    10
#define PAD   16               // zero rows per batch for AR lags
#define SEQP  (SEQ+PAD)        // 2064

// fp32 -> bf16 round-to-nearest-even
__device__ __forceinline__ u16 f2b(float f) {
    union { float f; uint32_t u; } v; v.f = f;
    uint32_t u = v.u + 0x7fffu + ((v.u >> 16) & 1u);
    return (u16)(u >> 16);
}
__device__ __forceinline__ float b2f(u16 h) {
    union { uint32_t u; float f; } v; v.u = ((uint32_t)h) << 16;
    return v.f;
}

// async global->LDS, 16B per lane; lds dest is wave-uniform base (+lane*16 by HW)
__device__ __forceinline__ void llds16(const u16* g, u16* l) {
    __builtin_amdgcn_global_load_lds(
        (const __attribute__((address_space(1))) uint32_t*)g,
        (__attribute__((address_space(3))) uint32_t*)l, 16, 0, 0);
}

// ---------------- fused prep kernel ----------------
#define PREP_X_END  8256
#define PREP_C_END  10304
#define PREP_M_END  14400

__global__ __launch_bounds__(256) void k_prep(
    const float* __restrict__ x, const float* __restrict__ B,
    const float* __restrict__ C, const float* __restrict__ M,
    u16* __restrict__ Xpad, u16* __restrict__ Btr, u16* __restrict__ Wall)
{
    __shared__ float tile[32][33];
    const int bid = blockIdx.x, tid = threadIdx.x;

    if (bid < PREP_X_END) {
        // inputs (4,2048,1024) f32 -> Xpad (4,2064,1024) bf16, 16 zero rows/batch
        int idx = bid * 256 + tid;
        long e = (long)idx * 4;
        int i = (int)(e & 1023);
        int row = (int)(e >> 10);
        int t = row % SEQP;
        int b = row / SEQP;
        ushort4 o;
        if (t < PAD) {
            o.x = 0; o.y = 0; o.z = 0; o.w = 0;
        } else {
            const float4 v = *(const float4*)(x + (((long)(b * SEQ + (t - PAD)) << 10) + i));
            o.x = f2b(v.x); o.y = f2b(v.y); o.z = f2b(v.z); o.w = f2b(v.w);
        }
        *(ushort4*)(Xpad + ((long)row << 10) + i) = o;
    } else if (bid < PREP_C_END) {
        // transpose+bf16: B -> Btr, C -> Wall group 0
        const int tb = bid - PREP_X_END;
        const float* in = (tb < 1024) ? B : C;
        u16* out = (tb < 1024) ? Btr : Wall;
        int lb = tb & 1023;
        int bx = lb & 31, by = lb >> 5;
        int tx = tid & 31, ty = tid >> 5;
#pragma unroll
        for (int j = 0; j < 4; j++)
            tile[ty + j * 8][tx] = in[(long)(by * 32 + ty + j * 8) * 1024 + bx * 32 + tx];
        __syncthreads();
#pragma unroll
        for (int j = 0; j < 4; j++)
            out[(long)(bx * 32 + ty + j * 8) * 1024 + by * 32 + tx] = f2b(tile[tx][ty + j * 8]);
    } else {
        // M (o,i,k) f32 -> Wall groups 1..10 as [k][o][i] bf16
        int idx = (bid - PREP_C_END) * 256 + tid;
        int o = idx >> 10, i = idx & 1023;
        const float* src = M + (long)idx * KX;
#pragma unroll
        for (int k = 0; k < KX; k++)
            Wall[((long)(k + 1) << 20) + ((long)o << 10) + i] = f2b(src[k]);
    }
}

// ---------------- scan kernels (chunked parallel linear scan) ----------------

__global__ void k_scan1(const u16* __restrict__ U, const float* __restrict__ A,
                        float* __restrict__ F) {
    int s = blockIdx.x * 256 + threadIdx.x;
    int bc = blockIdx.y;
    int b = bc >> 4, c = bc & 15;
    float a = A[s];
    const u16* u = U + (((long)(b * SEQ + c * 128)) << 10) + s;
    float f = 0.f;
#pragma unroll 8
    for (int j = 0; j < 128; j++) f = fmaf(a, f, b2f(u[(long)j << 10]));
    F[((long)bc << 10) + s] = f;
}

__global__ void k_scan2(const float* __restrict__ F, const float* __restrict__ A,
                        const float* __restrict__ h0, float* __restrict__ Carry) {
    int idx = blockIdx.x * 256 + threadIdx.x;
    int b = idx >> 10, s = idx & 1023;
    float a = A[s];
    float a128 = a;
#pragma unroll
    for (int q = 0; q < 7; q++) a128 *= a128;
    float carry = h0[s];
#pragma unroll
    for (int c = 0; c < 16; c++) {
        long off = ((long)(b * 16 + c) << 10) + s;
        Carry[off] = carry;
        carry = fmaf(a128, carry, F[off]);
    }
}

// writes H in-place over U (same element, same thread -> no hazard)
__global__ void k_scan3(u16* __restrict__ U, const float* __restrict__ A,
                        const float* __restrict__ Carry) {
    int s = blockIdx.x * 256 + threadIdx.x;
    int bc = blockIdx.y;
    int b = bc >> 4, c = bc & 15;
    float a = A[s];
    long base = (((long)(b * SEQ + c * 128)) << 10) + s;
    float h = Carry[((long)bc << 10) + s];
#pragma unroll 8
    for (int j = 0; j < 128; j++) {
        h = fmaf(a, h, b2f(U[base + ((long)j << 10)]));
        U[base + ((long)j << 10)] = f2b(h);
    }
}

// ---------------- round-0 grouped GEMM (used for U = X @ B only) ----------------
__global__ __launch_bounds__(256) void k_gemm(
    void* __restrict__ outv, const u16* __restrict__ Xpad,
    const u16* __restrict__ Hbf, const u16* __restrict__ W,
    int ngroups, int use_h, int bf16_out)
{
    __shared__ u16 Asl[160 * 64];        // 20 KB X slab
    __shared__ u16 Wb2[2][128 * 64];     // 2 x 16 KB

    const int tid  = threadIdx.x;
    const int wave = tid >> 6, lane = tid & 63;
    const int wm = wave >> 1, wn = wave & 1;
    const int quad = lane >> 4, l15 = lane & 15, l7 = lane & 7;

    const int col0 = blockIdx.x * 128;
    const int row0 = blockIdx.y * 128;
    const int bb = row0 >> 11;
    const long Xrow0 = (long)bb * SEQP + PAD + (row0 & (SEQ - 1));
    const long XslabBase = (Xrow0 - 16) << 10;
    const int lastg = ngroups - 1;

    f32x4 acc[4][4];
#pragma unroll
    for (int i = 0; i < 4; i++)
#pragma unroll
        for (int j = 0; j < 4; j++)
            acc[i][j] = (f32x4){0.f, 0.f, 0.f, 0.f};

    for (int k0 = 0; k0 < 1024; k0 += 64) {
#pragma unroll
        for (int q = 0; q < 5; q++) {
            int u = wave * 320 + q * 64 + lane;
            int row = u >> 3;
            int kc = (u & 7) ^ (row & 7);
            llds16(Xpad + XslabBase + ((long)row << 10) + k0 + kc * 8,
                   &Asl[(wave * 320 + q * 64) * 8]);
        }
        {
            int wsel = use_h ? 1 : 0;
            const u16* Wg = W + ((long)wsel << 20) + ((long)col0 << 10);
#pragma unroll
            for (int q = 0; q < 4; q++) {
                int u = wave * 256 + q * 64 + lane;
                int row = u >> 3;
                int kc = (u & 7) ^ (row & 7);
                llds16(Wg + ((long)row << 10) + k0 + kc * 8,
                       &Wb2[0][(wave * 256 + q * 64) * 8]);
            }
        }
        __syncthreads();

        for (int g = 0; g < ngroups; g++) {
            const bool isH = use_h && (g == lastg);
            if (isH) {
                const u16* Hb = Hbf + ((long)row0 << 10);
#pragma unroll
                for (int q = 0; q < 4; q++) {
                    int u = wave * 256 + q * 64 + lane;
                    int row = u >> 3;
                    int kc = (u & 7) ^ (row & 7);
                    llds16(Hb + ((long)row << 10) + k0 + kc * 8,
                           &Asl[(wave * 256 + q * 64) * 8]);
                }
                __syncthreads();
            }
            if (g < lastg) {
                int gn = g + 1;
                int wsel = use_h ? ((gn == lastg) ? 0 : gn + 1) : gn;
                const u16* Wg = W + ((long)wsel << 20) + ((long)col0 << 10);
                u16* dst = Wb2[gn & 1];
#pragma unroll
                for (int q = 0; q < 4; q++) {
                    int u = wave * 256 + q * 64 + lane;
                    int row = u >> 3;
                    int kc = (u & 7) ^ (row & 7);
                    llds16(Wg + ((long)row << 10) + k0 + kc * 8,
                           &dst[(wave * 256 + q * 64) * 8]);
                }
            }

            const int rbase = isH ? 0 : (16 - g);
            const int r7 = (l15 + rbase) & 7;
            const u16* Wrd = Wb2[g & 1];

            s16x8 af[4][2], bfr[4][2];
#pragma unroll
            for (int mi = 0; mi < 4; mi++) {
                int arow = rbase + wm * 64 + mi * 16 + l15;
#pragma unroll
                for (int kk = 0; kk < 2; kk++) {
                    int kca = ((kk * 4 + quad) ^ r7) << 3;
                    int kcb = ((kk * 4 + quad) ^ l7) << 3;
                    af[mi][kk]  = *(const s16x8*)&Asl[arow * 64 + kca];
                    bfr[mi][kk] = *(const s16x8*)&Wrd[(wn * 64 + mi * 16 + l15) * 64 + kcb];
                }
            }
#pragma unroll
            for (int mi = 0; mi < 4; mi++)
#pragma unroll
                for (int ni = 0; ni < 4; ni++) {
                    acc[mi][ni] = __builtin_amdgcn_mfma_f32_16x16x32_bf16(
                        af[mi][0], bfr[ni][0], acc[mi][ni], 0, 0, 0);
                    acc[mi][ni] = __builtin_amdgcn_mfma_f32_16x16x32_bf16(
                        af[mi][1], bfr[ni][1], acc[mi][ni], 0, 0, 0);
                }
            __syncthreads();
        }
    }

#pragma unroll
    for (int mi = 0; mi < 4; mi++) {
        int r = row0 + wm * 64 + mi * 16 + quad * 4;
#pragma unroll
        for (int ni = 0; ni < 4; ni++) {
            int c = col0 + wn * 64 + ni * 16 + l15;
            f32x4 v = acc[mi][ni];
            if (bf16_out) {
                u16* ob = (u16*)outv;
#pragma unroll
                for (int reg = 0; reg < 4; reg++)
                    ob[((long)(r + reg) << 10) + c] = f2b(v[reg]);
            } else {
                float* of = (float*)outv;
#pragma unroll
                for (int reg = 0; reg < 4; reg++)
                    of[((long)(r + reg) << 10) + c] = v[reg];
            }
        }
    }
}

// ---------------- gemm2: 256x128 tile, 8 waves, 2-phase steps, W ring-3 ----------------
// out[r][n] = sum_g sum_k A_g[r][k] * W'[g][n][k]; groups g=0..9 lags (W' = Wall
// group g+1), g=10 H (W' = Wall group 0 = C^T). Flat step s = kk0*11 + g.
// W slabs (128 cols x 64 k) in a 3-slot LDS ring; W(s+2) prefetched during step s
// (1 llds16/thread per phase), counted s_waitcnt vmcnt(2) at step end keeps it in
// flight across raw s_barriers. X slab (272 rows) restaged at g==0, H (256 rows,
// overwrites Asl rows 0..255) at g==10: restage issued BEFORE the W prefetch so
// vmcnt(1) completes it while keeping the prefetch in flight.
// vmem-op ledger (per wave): prologue X(5)+W0(2)+W1(2)=9, vmcnt(2) -> W1 in flight.
// steady step: +p0 +p1, tail vmcnt(2). restage step: +5(X)/+4(H) then +p0,
// vmcnt(1) -> restage complete, p0 in flight; tail +p1, vmcnt(2).
__global__ __launch_bounds__(512) void k_gemm8(
    float* __restrict__ out, const u16* __restrict__ Xpad,
    const u16* __restrict__ Hbf, const u16* __restrict__ W)
{
    __shared__ u16 Asl[272 * 64];        // 34 KB: X rows [Xrow0-9, Xrow0+263); H rows 0..255
    __shared__ u16 Wb[3][128 * 64];      // 3 x 16 KB ring

    const int tid  = threadIdx.x;
    const int wave = tid >> 6, lane = tid & 63;
    const int wm = wave >> 1, wn = wave & 1;          // 4M x 2N waves
    const int quad = lane >> 4, l15 = lane & 15, l7 = lane & 7;

    const int col0 = blockIdx.x * 128;
    const int row0 = blockIdx.y * 256;
    const int bb = row0 >> 11;
    const long Xrow0 = (long)bb * SEQP + PAD + (row0 & (SEQ - 1));
    const long XslabBase = (Xrow0 - 9) << 10;

    f32x4 acc[4][4];   // [mi][ni], per-wave 64x64 tile
#pragma unroll
    for (int i = 0; i < 4; i++)
#pragma unroll
        for (int j = 0; j < 4; j++)
            acc[i][j] = (f32x4){0.f, 0.f, 0.f, 0.f};

    // W slab stage: 1024 units of 16B, part p covers units [p*512, p*512+512)
    auto stageW = [&](int k0p, int wsel, int slot, int part) {
        const u16* Wg = W + ((long)wsel << 20) + ((long)col0 << 10);
        int u = part * 512 + tid;
        int row = u >> 3;
        int kc = (u & 7) ^ (row & 7);
        llds16(Wg + ((long)row << 10) + k0p + kc * 8,
               &Wb[slot][(part * 512 + wave * 64) * 8]);
    };
    // X slab: 2176 units (272 rows); each wave stages 272 units (4 full + 16 masked)
    auto stageX = [&](int k0p) {
#pragma unroll
        for (int q = 0; q < 4; q++) {
            int u = wave * 272 + q * 64 + lane;
            int row = u >> 3;
            int kc = (u & 7) ^ (row & 7);
            llds16(Xpad + XslabBase + ((long)row << 10) + k0p + kc * 8,
                   &Asl[(wave * 272 + q * 64) * 8]);
        }
        {
            int u = wave * 272 + 256 + lane;
            int row = u >> 3;
            int kc = (u & 7) ^ (row & 7);
            if (lane < 16)
                llds16(Xpad + XslabBase + ((long)row << 10) + k0p + kc * 8,
                       &Asl[(wave * 272 + 256) * 8]);
        }
    };
    // H slab: 2048 units (256 rows) into Asl rows 0..255
    auto stageH = [&](int k0p) {
        const u16* Hb = Hbf + ((long)row0 << 10);
#pragma unroll
        for (int q = 0; q < 4; q++) {
            int u = q * 512 + tid;
            int row = u >> 3;
            int kc = (u & 7) ^ (row & 7);
            llds16(Hb + ((long)row << 10) + k0p + kc * 8,
                   &Asl[(q * 512 + wave * 64) * 8]);
        }
    };

    // ---- prologue: X(0) + W(step0)->slot0 + W(step1)->slot1; keep W(step1) in flight ----
    stageX(0);
    stageW(0, 1, 0, 0); stageW(0, 1, 0, 1);   // step0: g=0 -> wsel 1
    stageW(0, 2, 1, 0); stageW(0, 2, 1, 1);   // step1: g=1 -> wsel 2
    asm volatile("s_waitcnt vmcnt(2)" ::: "memory");
    __builtin_amdgcn_s_barrier();

    int slot = 0;
    for (int kk0 = 0; kk0 < 16; ++kk0) {
        const int k0 = kk0 * 64;
        for (int g = 0; g < 11; ++g) {
            const bool isH = (g == 10);
            const bool restage = isH || (g == 0 && kk0 > 0);

            // prefetch coords for step s+2
            int g2 = g + 2, kk2 = kk0;
            if (g2 >= 11) { g2 -= 11; kk2 += 1; }
            const bool pf = (kk2 < 16);
            const int wsel2 = (g2 == 10) ? 0 : (g2 + 1);
            const int slot2 = (slot + 2 >= 3) ? slot + 2 - 3 : slot + 2;

            // ---- A-restage issues first (older than W(s+2)) ----
            if (isH)           stageH(k0);
            else if (restage)  stageX(k0);

            if (pf) stageW(kk2 * 64, wsel2, slot2, 0);

            if (restage) {
                if (pf) asm volatile("s_waitcnt vmcnt(1)" ::: "memory");
                else    asm volatile("s_waitcnt vmcnt(0)" ::: "memory");
                __builtin_amdgcn_s_barrier();
            }

            const int rbase = isH ? 0 : (9 - g);
            const u16* Wrd = &Wb[slot][0];

            // ---- P0: read bfr (8) + af mi=0,1 (4) ----
            s16x8 bfr[4][2], af[2][2];
#pragma unroll
            for (int ni = 0; ni < 4; ni++) {
                int brow = wn * 64 + ni * 16 + l15;
#pragma unroll
                for (int kk = 0; kk < 2; kk++) {
                    int kcb = ((kk * 4 + quad) ^ l7) << 3;
                    bfr[ni][kk] = *(const s16x8*)&Wrd[brow * 64 + kcb];
                }
            }
#pragma unroll
            for (int i = 0; i < 2; i++) {
                int arow = rbase + wm * 64 + i * 16 + l15;
                int r7 = arow & 7;
#pragma unroll
                for (int kk = 0; kk < 2; kk++) {
                    int kca = ((kk * 4 + quad) ^ r7) << 3;
                    af[i][kk] = *(const s16x8*)&Asl[arow * 64 + kca];
                }
            }
            __builtin_amdgcn_s_barrier();
            __builtin_amdgcn_s_setprio(1);
#pragma unroll
            for (int i = 0; i < 2; i++)
#pragma unroll
                for (int ni = 0; ni < 4; ni++) {
                    acc[i][ni] = __builtin_amdgcn_mfma_f32_16x16x32_bf16(
                        af[i][0], bfr[ni][0], acc[i][ni], 0, 0, 0);
                    acc[i][ni] = __builtin_amdgcn_mfma_f32_16x16x32_bf16(
                        af[i][1], bfr[ni][1], acc[i][ni], 0, 0, 0);
                }
            __builtin_amdgcn_s_setprio(0);
            __builtin_amdgcn_s_barrier();

            // ---- P1: read af mi=2,3 (4) ----
            s16x8 af2[2][2];
#pragma unroll
            for (int i = 0; i < 2; i++) {
                int arow = rbase + wm * 64 + (i + 2) * 16 + l15;
                int r7 = arow & 7;
#pragma unroll
                for (int kk = 0; kk < 2; kk++) {
                    int kca = ((kk * 4 + quad) ^ r7) << 3;
                    af2[i][kk] = *(const s16x8*)&Asl[arow * 64 + kca];
                }
            }
            if (pf) stageW(kk2 * 64, wsel2, slot2, 1);
            __builtin_amdgcn_s_barrier();
            __builtin_amdgcn_s_setprio(1);
#pragma unroll
            for (int i = 0; i < 2; i++)
#pragma unroll
                for (int ni = 0; ni < 4; ni++) {
                    acc[i + 2][ni] = __builtin_amdgcn_mfma_f32_16x16x32_bf16(
                        af2[i][0], bfr[ni][0], acc[i + 2][ni], 0, 0, 0);
                    acc[i + 2][ni] = __builtin_amdgcn_mfma_f32_16x16x32_bf16(
                        af2[i][1], bfr[ni][1], acc[i + 2][ni], 0, 0, 0);
                }
            __builtin_amdgcn_s_setprio(0);
            // step tail: W(s+1) retired, W(s+2) spans the barrier
            if (pf) asm volatile("s_waitcnt vmcnt(2)" ::: "memory");
            else    asm volatile("s_waitcnt vmcnt(0)" ::: "memory");
            __builtin_amdgcn_s_barrier();

            slot = (slot == 2) ? 0 : slot + 1;
        }
    }

    // ---- epilogue: C/D layout col=lane&15, row=quad*4+reg ----
#pragma unroll
    for (int mi = 0; mi < 4; mi++) {
        int r = row0 + wm * 64 + mi * 16 + quad * 4;
#pragma unroll
        for (int ni = 0; ni < 4; ni++) {
            int c = col0 + wn * 64 + ni * 16 + l15;
            f32x4 v = acc[mi][ni];
#pragma unroll
            for (int reg = 0; reg < 4; reg++)
                out[((long)(r + reg) << 10) + c] = v[reg];
        }
    }
}

// ---------------- launch ----------------

extern "C" void kernel_launch(void* const* d_in, const int* in_sizes, int n_in,
                              void* d_out, int out_size, void* d_ws, size_t ws_size,
                              hipStream_t stream) {
    const float* x  = (const float*)d_in[0];   // (4,2048,1024)
    const float* h0 = (const float*)d_in[1];   // (1024,)
    const float* A  = (const float*)d_in[2];   // (1024,)
    const float* B  = (const float*)d_in[3];   // (1024,1024)
    const float* C  = (const float*)d_in[4];   // (1024,1024)
    const float* M  = (const float*)d_in[5];   // (1024,1024,10)
    float* out = (float*)d_out;

    char* ws = (char*)d_ws;
    u16*   Xpad  = (u16*)  (ws);                      // 16,908,288
    u16*   Wall  = (u16*)  (ws + 16908288);           // 23,068,672 (group0 = C^T)
    u16*   Btr   = (u16*)  (ws + 39976960);           // 2,097,152
    u16*   Ubf   = (u16*)  (ws + 42074112);           // 16,777,216 (scan3 overwrites with H)
    float* F     = (float*)(ws + 58851328);           // 262,144
    float* Carry = (float*)(ws + 59113472);           // 262,144  (end ~59.4 MB)

    // fused conversions
    k_prep<<<dim3(PREP_M_END), dim3(256), 0, stream>>>(x, B, C, M, Xpad, Btr, Wall);

    // U = X @ B  (bf16 output)
    k_gemm<<<dim3(8, 64), dim3(256), 0, stream>>>(Ubf, Xpad, Ubf, Btr, 1, 0, 1);

    // chunked linear scan; scan3 turns Ubf into Hbf in-place
    k_scan1<<<dim3(4, 64), dim3(256), 0, stream>>>(Ubf, A, F);
    k_scan2<<<dim3(16), dim3(256), 0, stream>>>(F, A, h0, Carry);
    k_scan3<<<dim3(4, 64), dim3(256), 0, stream>>>(Ubf, A, Carry);

    // out = H @ C + sum_k shift_k(X) @ M_k   (11 K-groups)
    k_gemm8<<<dim3(8, 32), dim3(512), 0, stream>>>(out, Xpad, Ubf, Wall);
}

// Round 5
// 335.363 us; speedup vs baseline: 1.1304x; 1.1304x over previous
//
#include <hip/hip_runtime.h>
#include <stdint.h>

typedef unsigned short u16;
typedef __attribute__((ext_vector_type(4))) float f32x4;
typedef __attribute__((ext_vector_type(8))) short s16x8;

#define BATCH 4
#define SEQ   2048
#define DIM   1024   // D_IN = STATE = D_OUT
#define KX    10
#define PAD   16               // zero rows per batch for AR lags
#define SEQP  (SEQ+PAD)        // 2064

// fp32 -> bf16 round-to-nearest-even
__device__ __forceinline__ u16 f2b(float f) {
    union { float f; uint32_t u; } v; v.f = f;
    uint32_t u = v.u + 0x7fffu + ((v.u >> 16) & 1u);
    return (u16)(u >> 16);
}
__device__ __forceinline__ float b2f(u16 h) {
    union { uint32_t u; float f; } v; v.u = ((uint32_t)h) << 16;
    return v.f;
}

// async global->LDS, 16B per lane; lds dest is wave-uniform base (+lane*16 by HW)
__device__ __forceinline__ void llds16(const u16* g, u16* l) {
    __builtin_amdgcn_global_load_lds(
        (const __attribute__((address_space(1))) uint32_t*)g,
        (__attribute__((address_space(3))) uint32_t*)l, 16, 0, 0);
}

// ---------------- fused prep kernel ----------------
#define PREP_X_END  8256
#define PREP_C_END  10304
#define PREP_M_END  14400

__global__ __launch_bounds__(256) void k_prep(
    const float* __restrict__ x, const float* __restrict__ B,
    const float* __restrict__ C, const float* __restrict__ M,
    u16* __restrict__ Xpad, u16* __restrict__ Btr, u16* __restrict__ Wall)
{
    __shared__ float tile[32][33];
    const int bid = blockIdx.x, tid = threadIdx.x;

    if (bid < PREP_X_END) {
        // inputs (4,2048,1024) f32 -> Xpad (4,2064,1024) bf16, 16 zero rows/batch
        int idx = bid * 256 + tid;
        long e = (long)idx * 4;
        int i = (int)(e & 1023);
        int row = (int)(e >> 10);
        int t = row % SEQP;
        int b = row / SEQP;
        ushort4 o;
        if (t < PAD) {
            o.x = 0; o.y = 0; o.z = 0; o.w = 0;
        } else {
            const float4 v = *(const float4*)(x + (((long)(b * SEQ + (t - PAD)) << 10) + i));
            o.x = f2b(v.x); o.y = f2b(v.y); o.z = f2b(v.z); o.w = f2b(v.w);
        }
        *(ushort4*)(Xpad + ((long)row << 10) + i) = o;
    } else if (bid < PREP_C_END) {
        // transpose+bf16: B -> Btr, C -> Wall group 0
        const int tb = bid - PREP_X_END;
        const float* in = (tb < 1024) ? B : C;
        u16* out = (tb < 1024) ? Btr : Wall;
        int lb = tb & 1023;
        int bx = lb & 31, by = lb >> 5;
        int tx = tid & 31, ty = tid >> 5;
#pragma unroll
        for (int j = 0; j < 4; j++)
            tile[ty + j * 8][tx] = in[(long)(by * 32 + ty + j * 8) * 1024 + bx * 32 + tx];
        __syncthreads();
#pragma unroll
        for (int j = 0; j < 4; j++)
            out[(long)(bx * 32 + ty + j * 8) * 1024 + by * 32 + tx] = f2b(tile[tx][ty + j * 8]);
    } else {
        // M (o,i,k) f32 -> Wall groups 1..10 as [k][o][i] bf16
        int idx = (bid - PREP_C_END) * 256 + tid;
        int o = idx >> 10, i = idx & 1023;
        const float* src = M + (long)idx * KX;
#pragma unroll
        for (int k = 0; k < KX; k++)
            Wall[((long)(k + 1) << 20) + ((long)o << 10) + i] = f2b(src[k]);
    }
}

// ---------------- scan kernels (chunked parallel linear scan) ----------------

__global__ void k_scan1(const u16* __restrict__ U, const float* __restrict__ A,
                        float* __restrict__ F) {
    int s = blockIdx.x * 256 + threadIdx.x;
    int bc = blockIdx.y;
    int b = bc >> 4, c = bc & 15;
    float a = A[s];
    const u16* u = U + (((long)(b * SEQ + c * 128)) << 10) + s;
    float f = 0.f;
#pragma unroll 8
    for (int j = 0; j < 128; j++) f = fmaf(a, f, b2f(u[(long)j << 10]));
    F[((long)bc << 10) + s] = f;
}

__global__ void k_scan2(const float* __restrict__ F, const float* __restrict__ A,
                        const float* __restrict__ h0, float* __restrict__ Carry) {
    int idx = blockIdx.x * 256 + threadIdx.x;
    int b = idx >> 10, s = idx & 1023;
    float a = A[s];
    float a128 = a;
#pragma unroll
    for (int q = 0; q < 7; q++) a128 *= a128;
    float carry = h0[s];
#pragma unroll
    for (int c = 0; c < 16; c++) {
        long off = ((long)(b * 16 + c) << 10) + s;
        Carry[off] = carry;
        carry = fmaf(a128, carry, F[off]);
    }
}

// writes H in-place over U (same element, same thread -> no hazard)
__global__ void k_scan3(u16* __restrict__ U, const float* __restrict__ A,
                        const float* __restrict__ Carry) {
    int s = blockIdx.x * 256 + threadIdx.x;
    int bc = blockIdx.y;
    int b = bc >> 4, c = bc & 15;
    float a = A[s];
    long base = (((long)(b * SEQ + c * 128)) << 10) + s;
    float h = Carry[((long)bc << 10) + s];
#pragma unroll 8
    for (int j = 0; j < 128; j++) {
        h = fmaf(a, h, b2f(U[base + ((long)j << 10)]));
        U[base + ((long)j << 10)] = f2b(h);
    }
}

// ---------------- grouped GEMM: 128x64 tile, 2 waves, 4 blocks/CU ----------------
// out[r][n] = sum_g sum_k Aop_g[r][k] * W'[g][n][k]
// use_h=1 (11 groups): g in [0,9] -> A = Xpad rows lag g, W' = Wall group g+1 (M_g);
//                      g = 10    -> A = Hbf rows (lag 0), W' = Wall group 0 (C^T).
// use_h=0: g=0 -> A = Xpad lag 0, W' = W base (Btr).
// Same per-wave geometry / swizzle / sync structure as the verified 128x128
// round-0 kernel, retiled to 128 rows x 64 cols with 2 waves (both waves split M,
// share the W slab). LDS 36 KB -> 4 independent blocks/CU (vs 2): the m114
// wave-level TLP mechanism gets 4 barrier domains to overlap LDS-read and MFMA.
__global__ __launch_bounds__(128) void k_gemm(
    void* __restrict__ outv, const u16* __restrict__ Xpad,
    const u16* __restrict__ Hbf, const u16* __restrict__ W,
    int ngroups, int use_h, int bf16_out)
{
    __shared__ u16 Asl[160 * 64];        // 20 KB X slab [Xrow0-16, Xrow0+144); H reuses [0,128)
    __shared__ u16 Wb2[2][64 * 64];      // 2 x 8 KB (64 cols x 64 k)

    const int tid  = threadIdx.x;
    const int wave = tid >> 6, lane = tid & 63;     // 2 waves, both split M
    const int quad = lane >> 4, l15 = lane & 15, l7 = lane & 7;

    const int col0 = blockIdx.x * 64;
    const int row0 = blockIdx.y * 128;
    const int bb = row0 >> 11;
    const long Xrow0 = (long)bb * SEQP + PAD + (row0 & (SEQ - 1));
    const long XslabBase = (Xrow0 - 16) << 10;
    const int lastg = ngroups - 1;

    f32x4 acc[4][4];
#pragma unroll
    for (int i = 0; i < 4; i++)
#pragma unroll
        for (int j = 0; j < 4; j++)
            acc[i][j] = (f32x4){0.f, 0.f, 0.f, 0.f};

    for (int k0 = 0; k0 < 1024; k0 += 64) {
        // ---- stage X slab: 160 rows x 64 k = 1280 units of 16B, 10/thread ----
#pragma unroll
        for (int q = 0; q < 10; q++) {
            int u = wave * 640 + q * 64 + lane;
            int row = u >> 3;
            int kc = (u & 7) ^ (row & 7);
            llds16(Xpad + XslabBase + ((long)row << 10) + k0 + kc * 8,
                   &Asl[(wave * 640 + q * 64) * 8]);
        }
        // ---- stage W for g=0 into Wb2[0]: 512 units, 4/thread ----
        {
            int wsel = use_h ? 1 : 0;
            const u16* Wg = W + ((long)wsel << 20) + ((long)col0 << 10);
#pragma unroll
            for (int q = 0; q < 4; q++) {
                int u = wave * 256 + q * 64 + lane;
                int row = u >> 3;
                int kc = (u & 7) ^ (row & 7);
                llds16(Wg + ((long)row << 10) + k0 + kc * 8,
                       &Wb2[0][(wave * 256 + q * 64) * 8]);
            }
        }
        __syncthreads();

        for (int g = 0; g < ngroups; g++) {
            const bool isH = use_h && (g == lastg);
            if (isH) {
                // X slab done (previous barrier); overwrite rows [0,128) with H
                const u16* Hb = Hbf + ((long)row0 << 10);
#pragma unroll
                for (int q = 0; q < 8; q++) {
                    int u = wave * 512 + q * 64 + lane;
                    int row = u >> 3;
                    int kc = (u & 7) ^ (row & 7);
                    llds16(Hb + ((long)row << 10) + k0 + kc * 8,
                           &Asl[(wave * 512 + q * 64) * 8]);
                }
                __syncthreads();
            }
            // ---- prefetch next W into the other buffer (drained at end-of-g barrier) ----
            if (g < lastg) {
                int gn = g + 1;
                int wsel = use_h ? ((gn == lastg) ? 0 : gn + 1) : gn;
                const u16* Wg = W + ((long)wsel << 20) + ((long)col0 << 10);
                u16* dst = Wb2[gn & 1];
#pragma unroll
                for (int q = 0; q < 4; q++) {
                    int u = wave * 256 + q * 64 + lane;
                    int row = u >> 3;
                    int kc = (u & 7) ^ (row & 7);
                    llds16(Wg + ((long)row << 10) + k0 + kc * 8,
                           &dst[(wave * 256 + q * 64) * 8]);
                }
            }

            // ---- fragments (swizzled ds_read_b128) ----
            const int rbase = isH ? 0 : (16 - g);   // slab-local row offset for this lag
            const int r7 = (l15 + rbase) & 7;
            const u16* Wrd = Wb2[g & 1];

            s16x8 af[4][2], bfr[4][2];
#pragma unroll
            for (int mi = 0; mi < 4; mi++) {
                int arow = rbase + wave * 64 + mi * 16 + l15;
#pragma unroll
                for (int kk = 0; kk < 2; kk++) {
                    int kca = ((kk * 4 + quad) ^ r7) << 3;
                    int kcb = ((kk * 4 + quad) ^ l7) << 3;
                    af[mi][kk]  = *(const s16x8*)&Asl[arow * 64 + kca];
                    bfr[mi][kk] = *(const s16x8*)&Wrd[(mi * 16 + l15) * 64 + kcb];
                }
            }
#pragma unroll
            for (int mi = 0; mi < 4; mi++)
#pragma unroll
                for (int ni = 0; ni < 4; ni++) {
                    acc[mi][ni] = __builtin_amdgcn_mfma_f32_16x16x32_bf16(
                        af[mi][0], bfr[ni][0], acc[mi][ni], 0, 0, 0);
                    acc[mi][ni] = __builtin_amdgcn_mfma_f32_16x16x32_bf16(
                        af[mi][1], bfr[ni][1], acc[mi][ni], 0, 0, 0);
                }
            __syncthreads();
        }
    }

    // ---- epilogue: C/D layout col=lane&15, row=quad*4+reg ----
#pragma unroll
    for (int mi = 0; mi < 4; mi++) {
        int r = row0 + wave * 64 + mi * 16 + quad * 4;
#pragma unroll
        for (int ni = 0; ni < 4; ni++) {
            int c = col0 + ni * 16 + l15;
            f32x4 v = acc[mi][ni];
            if (bf16_out) {
                u16* ob = (u16*)outv;
#pragma unroll
                for (int reg = 0; reg < 4; reg++)
                    ob[((long)(r + reg) << 10) + c] = f2b(v[reg]);
            } else {
                float* of = (float*)outv;
#pragma unroll
                for (int reg = 0; reg < 4; reg++)
                    of[((long)(r + reg) << 10) + c] = v[reg];
            }
        }
    }
}

// ---------------- launch ----------------

extern "C" void kernel_launch(void* const* d_in, const int* in_sizes, int n_in,
                              void* d_out, int out_size, void* d_ws, size_t ws_size,
                              hipStream_t stream) {
    const float* x  = (const float*)d_in[0];   // (4,2048,1024)
    const float* h0 = (const float*)d_in[1];   // (1024,)
    const float* A  = (const float*)d_in[2];   // (1024,)
    const float* B  = (const float*)d_in[3];   // (1024,1024)
    const float* C  = (const float*)d_in[4];   // (1024,1024)
    const float* M  = (const float*)d_in[5];   // (1024,1024,10)
    float* out = (float*)d_out;

    char* ws = (char*)d_ws;
    u16*   Xpad  = (u16*)  (ws);                      // 16,908,288
    u16*   Wall  = (u16*)  (ws + 16908288);           // 23,068,672 (group0 = C^T)
    u16*   Btr   = (u16*)  (ws + 39976960);           // 2,097,152
    u16*   Ubf   = (u16*)  (ws + 42074112);           // 16,777,216 (scan3 overwrites with H)
    float* F     = (float*)(ws + 58851328);           // 262,144
    float* Carry = (float*)(ws + 59113472);           // 262,144  (end ~59.4 MB)

    // fused conversions
    k_prep<<<dim3(PREP_M_END), dim3(256), 0, stream>>>(x, B, C, M, Xpad, Btr, Wall);

    // U = X @ B  (bf16 output)
    k_gemm<<<dim3(16, 64), dim3(128), 0, stream>>>(Ubf, Xpad, Ubf, Btr, 1, 0, 1);

    // chunked linear scan; scan3 turns Ubf into Hbf in-place
    k_scan1<<<dim3(4, 64), dim3(256), 0, stream>>>(Ubf, A, F);
    k_scan2<<<dim3(16), dim3(256), 0, stream>>>(F, A, h0, Carry);
    k_scan3<<<dim3(4, 64), dim3(256), 0, stream>>>(Ubf, A, Carry);

    // out = H @ C + sum_k shift_k(X) @ M_k   (11 K-groups)
    k_gemm<<<dim3(16, 64), dim3(128), 0, stream>>>(out, Xpad, Ubf, Wall, 11, 1, 0);
}